// Round 1
// baseline (77.906 us; speedup 1.0000x reference)
//
#include <hip/hip_runtime.h>
#include <math.h>

#define EPS 1e-6f

__device__ __forceinline__ float logit_f(float p) {
    p = fminf(fmaxf(p, EPS), 1.0f - EPS);
    return __logf(p) - __logf(1.0f - p);
}

__device__ __forceinline__ float tanh_fast(float x) {
    // tanh(x) = 1 - 2/(exp(2x)+1); saturates correctly for |x| large.
    float e = __expf(2.0f * x);
    return 1.0f - 2.0f / (e + 1.0f);
}

__global__ __launch_bounds__(256) void attn_fusion_kernel(
    const float* __restrict__ p,
    const float* __restrict__ W1,
    const float* __restrict__ b1,
    const float* __restrict__ W2,
    const float* __restrict__ b2,
    float* __restrict__ out_prob,   // [B]
    float* __restrict__ out_a,      // [B,3]
    int ngroups)                    // B/4 groups of 4 points
{
    int t = blockIdx.x * blockDim.x + threadIdx.x;
    if (t >= ngroups) return;

    // Wave-uniform weight loads with constant indices -> SGPRs via s_load.
    float w1[8][3], bb1[8], w2[3][8], bb2[3];
    #pragma unroll
    for (int j = 0; j < 8; ++j) {
        #pragma unroll
        for (int k = 0; k < 3; ++k) w1[j][k] = W1[j * 3 + k];
        bb1[j] = b1[j];
    }
    #pragma unroll
    for (int k = 0; k < 3; ++k) {
        #pragma unroll
        for (int j = 0; j < 8; ++j) w2[k][j] = W2[k * 8 + j];
        bb2[k] = b2[k];
    }

    // 4 points = 12 floats = 3 float4 loads.
    const float4* pv = reinterpret_cast<const float4*>(p) + (size_t)t * 3;
    float4 v0 = pv[0];
    float4 v1 = pv[1];
    float4 v2 = pv[2];
    float in[12] = {v0.x, v0.y, v0.z, v0.w,
                    v1.x, v1.y, v1.z, v1.w,
                    v2.x, v2.y, v2.z, v2.w};

    float probs[4];
    float av[12];

    #pragma unroll
    for (int q = 0; q < 4; ++q) {
        float z0 = logit_f(in[q * 3 + 0]);
        float z1 = logit_f(in[q * 3 + 1]);
        float z2 = logit_f(in[q * 3 + 2]);

        float s0 = bb2[0], s1 = bb2[1], s2 = bb2[2];
        #pragma unroll
        for (int j = 0; j < 8; ++j) {
            float pre = fmaf(w1[j][0], z0,
                        fmaf(w1[j][1], z1,
                        fmaf(w1[j][2], z2, bb1[j])));
            float h = tanh_fast(pre);
            s0 = fmaf(w2[0][j], h, s0);
            s1 = fmaf(w2[1][j], h, s1);
            s2 = fmaf(w2[2][j], h, s2);
        }

        float m = fmaxf(s0, fmaxf(s1, s2));
        float e0 = __expf(s0 - m);
        float e1 = __expf(s1 - m);
        float e2 = __expf(s2 - m);
        float inv = 1.0f / (e0 + e1 + e2);
        float a0 = e0 * inv, a1 = e1 * inv, a2 = e2 * inv;

        av[q * 3 + 0] = a0;
        av[q * 3 + 1] = a1;
        av[q * 3 + 2] = a2;

        float fl = fmaf(a0, z0, fmaf(a1, z1, a2 * z2));
        probs[q] = 1.0f / (1.0f + __expf(-fl));
    }

    reinterpret_cast<float4*>(out_prob)[t] =
        make_float4(probs[0], probs[1], probs[2], probs[3]);

    float4* ao = reinterpret_cast<float4*>(out_a) + (size_t)t * 3;
    ao[0] = make_float4(av[0], av[1], av[2],  av[3]);
    ao[1] = make_float4(av[4], av[5], av[6],  av[7]);
    ao[2] = make_float4(av[8], av[9], av[10], av[11]);
}

// Scalar tail kernel for B % 4 != 0 (not hit at B=8388608, kept for safety).
__global__ void attn_fusion_tail(
    const float* __restrict__ p,
    const float* __restrict__ W1,
    const float* __restrict__ b1,
    const float* __restrict__ W2,
    const float* __restrict__ b2,
    float* __restrict__ out_prob,
    float* __restrict__ out_a,
    int start, int B)
{
    int i = start + blockIdx.x * blockDim.x + threadIdx.x;
    if (i >= B) return;

    float z[3];
    #pragma unroll
    for (int k = 0; k < 3; ++k) z[k] = logit_f(p[(size_t)i * 3 + k]);

    float s[3] = {b2[0], b2[1], b2[2]};
    #pragma unroll
    for (int j = 0; j < 8; ++j) {
        float pre = b1[j];
        #pragma unroll
        for (int k = 0; k < 3; ++k) pre = fmaf(W1[j * 3 + k], z[k], pre);
        float h = tanh_fast(pre);
        #pragma unroll
        for (int k = 0; k < 3; ++k) s[k] = fmaf(W2[k * 8 + j], h, s[k]);
    }
    float m = fmaxf(s[0], fmaxf(s[1], s[2]));
    float e0 = __expf(s[0] - m), e1 = __expf(s[1] - m), e2 = __expf(s[2] - m);
    float inv = 1.0f / (e0 + e1 + e2);
    float a0 = e0 * inv, a1 = e1 * inv, a2 = e2 * inv;
    out_a[(size_t)i * 3 + 0] = a0;
    out_a[(size_t)i * 3 + 1] = a1;
    out_a[(size_t)i * 3 + 2] = a2;
    float fl = fmaf(a0, z[0], fmaf(a1, z[1], a2 * z[2]));
    out_prob[i] = 1.0f / (1.0f + __expf(-fl));
}

extern "C" void kernel_launch(void* const* d_in, const int* in_sizes, int n_in,
                              void* d_out, int out_size, void* d_ws, size_t ws_size,
                              hipStream_t stream) {
    const float* p  = (const float*)d_in[0];
    const float* W1 = (const float*)d_in[1];
    const float* b1 = (const float*)d_in[2];
    const float* W2 = (const float*)d_in[3];
    const float* b2 = (const float*)d_in[4];

    int B = in_sizes[0] / 3;
    float* out_prob = (float*)d_out;        // [B]
    float* out_a    = (float*)d_out + B;    // [B,3]

    int ngroups = B / 4;
    if (ngroups > 0) {
        int block = 256;
        int grid = (ngroups + block - 1) / block;
        attn_fusion_kernel<<<grid, block, 0, stream>>>(
            p, W1, b1, W2, b2, out_prob, out_a, ngroups);
    }
    int tail = B - ngroups * 4;
    if (tail > 0) {
        attn_fusion_tail<<<1, 64, 0, stream>>>(
            p, W1, b1, W2, b2, out_prob, out_a, ngroups * 4, B);
    }
}

// Round 2
// 42.952 us; speedup vs baseline: 1.8138x; 1.8138x over previous
//
#include <hip/hip_runtime.h>
#include <math.h>

#define EPS 1e-6f
#define INVLN2 1.4426950408889634f   // 1/ln(2)
#define TWOINVLN2 2.8853900817779268f // 2/ln(2)

// Native-instruction wrappers: v_log_f32 (log2), v_exp_f32 (exp2), v_rcp_f32, v_med3_f32
__device__ __forceinline__ float log2_hw(float x) { return __builtin_amdgcn_logf(x); }
__device__ __forceinline__ float exp2_hw(float x) { return __builtin_amdgcn_exp2f(x); }
__device__ __forceinline__ float rcp_hw(float x)  { return __builtin_amdgcn_rcpf(x); }
__device__ __forceinline__ float med3_hw(float x, float lo, float hi) {
    return __builtin_amdgcn_fmed3f(x, lo, hi);
}

// logit in log2 units: log2(p) - log2(1-p)  ( = logit(p)/ln2 )
__device__ __forceinline__ float logit_l2(float p) {
    float pc = med3_hw(p, EPS, 1.0f - EPS);
    return log2_hw(pc) - log2_hw(1.0f - pc);
}

__global__ __launch_bounds__(256) void attn_fusion_kernel(
    const float* __restrict__ p,
    const float* __restrict__ W1,
    const float* __restrict__ b1,
    const float* __restrict__ W2,
    const float* __restrict__ b2,
    float* __restrict__ out_prob,   // [B]
    float* __restrict__ out_a,      // [B,3]
    int ngroups)                    // B/4 groups of 4 points
{
    int t = blockIdx.x * blockDim.x + threadIdx.x;
    if (t >= ngroups) return;

    // Wave-uniform weight loads with constant indices -> SGPRs via s_load.
    float w1[8][3], b1s[8], w2[3][8], bb2[3];
    #pragma unroll
    for (int j = 0; j < 8; ++j) {
        #pragma unroll
        for (int k = 0; k < 3; ++k) w1[j][k] = W1[j * 3 + k];
        b1s[j] = b1[j] * TWOINVLN2;   // bias prescaled: exp(2*pre) = exp2(W1.zz + b1s)
    }
    #pragma unroll
    for (int k = 0; k < 3; ++k) {
        #pragma unroll
        for (int j = 0; j < 8; ++j) w2[k][j] = W2[k * 8 + j];
        bb2[k] = b2[k];
    }

    // 4 points = 12 floats = 3 float4 loads.
    const float4* pv = reinterpret_cast<const float4*>(p) + (size_t)t * 3;
    float4 v0 = pv[0];
    float4 v1 = pv[1];
    float4 v2 = pv[2];
    float in[12] = {v0.x, v0.y, v0.z, v0.w,
                    v1.x, v1.y, v1.z, v1.w,
                    v2.x, v2.y, v2.z, v2.w};

    float probs[4];
    float av[12];

    #pragma unroll
    for (int q = 0; q < 4; ++q) {
        // z in log2 units
        float zl0 = logit_l2(in[q * 3 + 0]);
        float zl1 = logit_l2(in[q * 3 + 1]);
        float zl2 = logit_l2(in[q * 3 + 2]);
        // tanh-arg space: zz = 2*zl  (so exp(2*pre) = exp2(W1.zz + b1s))
        float zz0 = zl0 + zl0;
        float zz1 = zl1 + zl1;
        float zz2 = zl2 + zl2;

        float s0 = bb2[0], s1 = bb2[1], s2 = bb2[2];
        #pragma unroll
        for (int j = 0; j < 8; ++j) {
            float arg = fmaf(w1[j][0], zz0,
                        fmaf(w1[j][1], zz1,
                        fmaf(w1[j][2], zz2, b1s[j])));
            float E = exp2_hw(arg);                 // = exp(2*pre)
            float r = rcp_hw(E + 1.0f);
            float h = fmaf(-2.0f, r, 1.0f);         // tanh(pre)
            s0 = fmaf(w2[0][j], h, s0);
            s1 = fmaf(w2[1][j], h, s1);
            s2 = fmaf(w2[2][j], h, s2);
        }

        // softmax without max-subtract: |s| <= |b2| + sum|W2| ~ 3.4, no overflow
        float e0 = exp2_hw(s0 * INVLN2);
        float e1 = exp2_hw(s1 * INVLN2);
        float e2 = exp2_hw(s2 * INVLN2);
        float rden = rcp_hw(e0 + e1 + e2);
        float a0 = e0 * rden, a1 = e1 * rden, a2 = e2 * rden;

        av[q * 3 + 0] = a0;
        av[q * 3 + 1] = a1;
        av[q * 3 + 2] = a2;

        // fused_logit / ln2 = sum(a * zl2); sigmoid absorbs ln2 via exp2
        float fl2 = fmaf(a0, zl0, fmaf(a1, zl1, a2 * zl2));
        probs[q] = rcp_hw(1.0f + exp2_hw(-fl2));
    }

    reinterpret_cast<float4*>(out_prob)[t] =
        make_float4(probs[0], probs[1], probs[2], probs[3]);

    float4* ao = reinterpret_cast<float4*>(out_a) + (size_t)t * 3;
    ao[0] = make_float4(av[0], av[1], av[2],  av[3]);
    ao[1] = make_float4(av[4], av[5], av[6],  av[7]);
    ao[2] = make_float4(av[8], av[9], av[10], av[11]);
}

// Scalar tail kernel for B % 4 != 0 (not hit at B=8388608, kept for safety).
__global__ void attn_fusion_tail(
    const float* __restrict__ p,
    const float* __restrict__ W1,
    const float* __restrict__ b1,
    const float* __restrict__ W2,
    const float* __restrict__ b2,
    float* __restrict__ out_prob,
    float* __restrict__ out_a,
    int start, int B)
{
    int i = start + blockIdx.x * blockDim.x + threadIdx.x;
    if (i >= B) return;

    float zl[3];
    #pragma unroll
    for (int k = 0; k < 3; ++k) zl[k] = logit_l2(p[(size_t)i * 3 + k]);

    float s[3] = {b2[0], b2[1], b2[2]};
    #pragma unroll
    for (int j = 0; j < 8; ++j) {
        float arg = b1[j] * TWOINVLN2;
        #pragma unroll
        for (int k = 0; k < 3; ++k) arg = fmaf(W1[j * 3 + k], zl[k] + zl[k], arg);
        float E = exp2_hw(arg);
        float r = rcp_hw(E + 1.0f);
        float h = fmaf(-2.0f, r, 1.0f);
        #pragma unroll
        for (int k = 0; k < 3; ++k) s[k] = fmaf(W2[k * 8 + j], h, s[k]);
    }
    float e0 = exp2_hw(s[0] * INVLN2);
    float e1 = exp2_hw(s[1] * INVLN2);
    float e2 = exp2_hw(s[2] * INVLN2);
    float rden = rcp_hw(e0 + e1 + e2);
    float a0 = e0 * rden, a1 = e1 * rden, a2 = e2 * rden;
    out_a[(size_t)i * 3 + 0] = a0;
    out_a[(size_t)i * 3 + 1] = a1;
    out_a[(size_t)i * 3 + 2] = a2;
    float fl2 = fmaf(a0, zl[0], fmaf(a1, zl[1], a2 * zl[2]));
    out_prob[i] = rcp_hw(1.0f + exp2_hw(-fl2));
}

extern "C" void kernel_launch(void* const* d_in, const int* in_sizes, int n_in,
                              void* d_out, int out_size, void* d_ws, size_t ws_size,
                              hipStream_t stream) {
    const float* p  = (const float*)d_in[0];
    const float* W1 = (const float*)d_in[1];
    const float* b1 = (const float*)d_in[2];
    const float* W2 = (const float*)d_in[3];
    const float* b2 = (const float*)d_in[4];

    int B = in_sizes[0] / 3;
    float* out_prob = (float*)d_out;        // [B]
    float* out_a    = (float*)d_out + B;    // [B,3]

    int ngroups = B / 4;
    if (ngroups > 0) {
        int block = 256;
        int grid = (ngroups + block - 1) / block;
        attn_fusion_kernel<<<grid, block, 0, stream>>>(
            p, W1, b1, W2, b2, out_prob, out_a, ngroups);
    }
    int tail = B - ngroups * 4;
    if (tail > 0) {
        attn_fusion_tail<<<1, 64, 0, stream>>>(
            p, W1, b1, W2, b2, out_prob, out_a, ngroups * 4, B);
    }
}